// Round 4
// baseline (391.971 us; speedup 1.0000x reference)
//
#include <hip/hip_runtime.h>

// Problem constants (fixed by the reference)
#define Bdim   8
#define Cdim   2
#define Fdim   1024
#define Tdim   1024
#define NB     64
#define BWb    16
#define EMB    128
#define FEAT   64      // C * BW * 2
#define TILE_T 64
#define NTHR   256
#define NTILE  4       // t-tiles per block (pipelined)
#define EPSV   1e-5f

// MFMA fragment types (guide §3: 8 bf16 = 4 VGPRs, 4 f32 accum)
typedef __attribute__((ext_vector_type(8))) short bf16x8;
typedef __attribute__((ext_vector_type(4))) float f32x4;

// round-to-nearest-even fp32 -> bf16 (values are finite, no NaN handling needed)
__device__ __forceinline__ unsigned short f2bf(float x) {
    union { float f; unsigned u; } v; v.f = x;
    const unsigned r = v.u + 0x7FFFu + ((v.u >> 16) & 1u);
    return (unsigned short)(r >> 16);
}
__device__ __forceinline__ float bf2f(unsigned short b) {
    union { float f; unsigned u; } v; v.u = ((unsigned)b) << 16;
    return v.f;
}

// ---------------------------------------------------------------------------
// Pre-pass (verified round 3): fc_w fp32 [n][f][e] -> bf16 hi/lo in workspace,
// 32 KB per band, fragment XOR swizzle pre-applied so the main kernel does a
// LINEAR identity copy into LDS.
//   band n: bytes [n*32768, +16384) = hi, [+16384, +32768) = lo
//   within each: addr = e*128 + ((f/8) ^ (e&7))*16
// ---------------------------------------------------------------------------
__global__ __launch_bounds__(256) void conv_w_kernel(
    const float* __restrict__ fcw, unsigned char* __restrict__ ws)
{
    const int n  = blockIdx.x;
    const int e  = threadIdx.x & 127;
    const int fh = (threadIdx.x >> 7) * 32;
    const float* wsrc = fcw + (size_t)n * FEAT * EMB + e;
    float wv[32];
#pragma unroll
    for (int i = 0; i < 32; ++i)
        wv[i] = wsrc[(size_t)(fh + i) * EMB];

    char* const whb = (char*)ws + (size_t)n * 32768 + e * 128;
    char* const wlb = whb + 16384;
#pragma unroll
    for (int cc = 0; cc < 4; ++cc) {
        unsigned hw[4], lw[4];
#pragma unroll
        for (int j = 0; j < 4; ++j) {
            const float x0 = wv[cc * 8 + 2 * j];
            const float x1 = wv[cc * 8 + 2 * j + 1];
            const unsigned short h0 = f2bf(x0), h1 = f2bf(x1);
            hw[j] = (unsigned)h0 | ((unsigned)h1 << 16);
            lw[j] = (unsigned)f2bf(x0 - bf2f(h0))
                  | ((unsigned)f2bf(x1 - bf2f(h1)) << 16);
        }
        const int cs = ((fh >> 3) + cc) ^ (e & 7);
        *(uint4*)(whb + cs * 16) = make_uint4(hw[0], hw[1], hw[2], hw[3]);
        *(uint4*)(wlb + cs * 16) = make_uint4(lw[0], lw[1], lw[2], lw[3]);
    }
}

// ---------------------------------------------------------------------------
// Pipelined main kernel. Grid 2048 x 256 thr. Each block: one (b,n) band and
// NTILE=4 consecutive t-tiles of 64, double-buffered xs, W staged ONCE.
// Per-iteration phase internals are byte-identical to the round-1/3 verified
// kernel; only the loop/double-buffer structure is new.
//   iter tt: [issue next-tile global loads -> VGPR]  (T14 issue-early)
//            stats(cur) ; bar ; norm-read(cur)->regs ; bar ;
//            overlay-write A(cur) + ds_write staged tile -> nxt ; bar ;
//            GEMM(cur) + stores.
// Hazards: stats-bar of iter tt orders GEMM(tt-1) reads before any write to
// that buffer in iter tt (barriers are block-wide). Stage-write(nxt) in tt is
// 2 barriers after GEMM(tt-1) read nxt. All verified phase-local orderings
// unchanged. LDS: 2*16K (xs) + 32K (W) + ~1.5K = 66 KB -> 2 blocks/CU.
// ---------------------------------------------------------------------------
__global__ __launch_bounds__(NTHR, 2) void bandsplit_pipe(
    const float* __restrict__ xr, const float* __restrict__ xi,
    const float* __restrict__ lnw, const float* __restrict__ lnb,
    const unsigned char* __restrict__ whl, const float* __restrict__ fcb,
    float* __restrict__ out)
{
    __shared__ __align__(16) float xs2[2][FEAT][TILE_T];        // 32 KB
    __shared__ __align__(16) unsigned short w_hl[2][EMB][FEAT]; // 32 KB (pre-swizzled)
    __shared__ float sb[EMB];
    __shared__ float slnw[FEAT];
    __shared__ float slnb[FEAT];
    __shared__ float smu[TILE_T];
    __shared__ float srs[TILE_T];

    const int tid  = threadIdx.x;
    const int lane = tid & 63;
    const int wav  = tid >> 6;
    const int bid  = blockIdx.x;
    const int tg   = bid & 3;           // t-chunk of 4 tiles
    const int n    = (bid >> 2) & 63;   // band
    const int b    = bid >> 8;          // batch
    const int tci  = tg * NTILE;        // first t-tile index (of 16)

    // Per-thread staging map (identical math to verified phase 1): for
    // k = 0..3, v = tid + k*256 -> (f, tq); psrc[k] points at t=0 column.
    const float* psrc[4];
    int fk[4], tqk[4];
#pragma unroll
    for (int k = 0; k < 4; ++k) {
        const int v  = tid + k * NTHR;
        const int f  = v >> 4;
        const int tq = v & 15;
        const int c  = f >> 5;
        const int w  = (f >> 1) & 15;
        fk[k]  = f;
        tqk[k] = tq;
        psrc[k] = ((f & 1) ? xi : xr)
                + ((size_t)(b * Cdim + c) * Fdim + (n * BWb + w)) * Tdim + tq * 4;
    }

    // ---- Prologue: W copy (linear, verified), consts, tile-0 stage ----
    {
        const uint4* wsrc = (const uint4*)(whl + (size_t)n * 32768);
        uint4* wdst = (uint4*)&w_hl[0][0][0];
#pragma unroll
        for (int k = 0; k < 8; ++k)
            wdst[tid + k * NTHR] = wsrc[tid + k * NTHR];
    }
    if (tid < EMB)            sb[tid]              = fcb[n * EMB + tid];
    else if (tid < EMB + 64)  slnw[tid - EMB]      = lnw[n * FEAT + (tid - EMB)];
    else if (tid < EMB + 128) slnb[tid - EMB - 64] = lnb[n * FEAT + (tid - EMB - 64)];
#pragma unroll
    for (int k = 0; k < 4; ++k)
        *(float4*)&xs2[0][fk[k]][tqk[k] * 4] = *(const float4*)(psrc[k] + tci * TILE_T);
    __syncthreads();

    const int lr   = lane & 15;
    const int lh   = lane >> 4;
    const int trow = wav * 16;
    const char* const whb = (const char*)&w_hl[0][0][0];
    const char* const wlb = whb + 16384;

    for (int tt = 0; tt < NTILE; ++tt) {
        const int cur = tt & 1;
        const int t0g = (tci + tt) * TILE_T;
        char* const ab = (char*)&xs2[cur][0][0];

        // -- issue next-tile global loads early (hide under this iter) --
        float4 stg[4];
        if (tt < NTILE - 1) {
#pragma unroll
            for (int k = 0; k < 4; ++k)
                stg[k] = *(const float4*)(psrc[k] + t0g + TILE_T);
        }

        // -- stats (verified phase 2) --
        {
            const int t = tid >> 2;
            const int p = tid & 3;
            float s = 0.f, ss = 0.f;
#pragma unroll
            for (int j = 0; j < 16; ++j) {
                const float v = xs2[cur][p * 16 + j][t];
                s += v; ss += v * v;
            }
            s += __shfl_xor(s, 1); ss += __shfl_xor(ss, 1);
            s += __shfl_xor(s, 2); ss += __shfl_xor(ss, 2);
            if (p == 0) {
                const float mu  = s * (1.f / 64.f);
                const float var = ss * (1.f / 64.f) - mu * mu;
                smu[t] = mu;
                srs[t] = rsqrtf(var + EPSV);
            }
        }
        __syncthreads();

        // -- normalize + transpose + bf16 hi/lo split to regs (verified) --
        uint4 hq[2], lq[2];
        {
            const int t = lane;
            const float mu = smu[t], rsv = srs[t];
#pragma unroll
            for (int u = 0; u < 2; ++u) {
                const int fc = wav + u * 4;
                float xv[8];
#pragma unroll
                for (int j = 0; j < 8; ++j) xv[j] = xs2[cur][fc * 8 + j][t];
                unsigned hw[4], lw[4];
#pragma unroll
                for (int j = 0; j < 4; ++j) {
                    const int f0 = fc * 8 + 2 * j;
                    const float xn0 = (xv[2 * j]     - mu) * rsv * slnw[f0]     + slnb[f0];
                    const float xn1 = (xv[2 * j + 1] - mu) * rsv * slnw[f0 + 1] + slnb[f0 + 1];
                    const unsigned short h0 = f2bf(xn0), h1 = f2bf(xn1);
                    hw[j] = (unsigned)h0 | ((unsigned)h1 << 16);
                    lw[j] = (unsigned)f2bf(xn0 - bf2f(h0))
                          | ((unsigned)f2bf(xn1 - bf2f(h1)) << 16);
                }
                hq[u] = make_uint4(hw[0], hw[1], hw[2], hw[3]);
                lq[u] = make_uint4(lw[0], lw[1], lw[2], lw[3]);
            }
        }
        __syncthreads();   // all reads of xs2[cur] done -> overlay safe

        // -- overlay-write A(cur) + write staged next tile into nxt --
        {
            const int t = lane;
#pragma unroll
            for (int u = 0; u < 2; ++u) {
                const int fc = wav + u * 4;
                const int cs = fc ^ (t & 7);
                *(uint4*)(ab +        t * 128 + cs * 16) = hq[u];
                *(uint4*)(ab + 8192 + t * 128 + cs * 16) = lq[u];
            }
        }
        if (tt < NTILE - 1) {
            const int nxt = cur ^ 1;
#pragma unroll
            for (int k = 0; k < 4; ++k)
                *(float4*)&xs2[nxt][fk[k]][tqk[k] * 4] = stg[k];
        }
        __syncthreads();

        // -- MFMA GEMM (verified phase 4) --
        f32x4 acc[8];
        const f32x4 zero = {0.f, 0.f, 0.f, 0.f};
#pragma unroll
        for (int et = 0; et < 8; ++et) acc[et] = zero;

#pragma unroll
        for (int ks = 0; ks < 2; ++ks) {
            const int ta = trow + lr;
            const int ca = (ks * 4 + lh) ^ (ta & 7);
            const bf16x8 ahf = *(const bf16x8*)(ab +        ta * 128 + ca * 16);
            const bf16x8 alf = *(const bf16x8*)(ab + 8192 + ta * 128 + ca * 16);
#pragma unroll
            for (int et = 0; et < 8; ++et) {
                const int er = et * 16 + lr;
                const int cw = (ks * 4 + lh) ^ (er & 7);
                const bf16x8 whf = *(const bf16x8*)(whb + er * 128 + cw * 16);
                const bf16x8 wlf = *(const bf16x8*)(wlb + er * 128 + cw * 16);
                acc[et] = __builtin_amdgcn_mfma_f32_16x16x32_bf16(ahf, whf, acc[et], 0, 0, 0);
                acc[et] = __builtin_amdgcn_mfma_f32_16x16x32_bf16(ahf, wlf, acc[et], 0, 0, 0);
                acc[et] = __builtin_amdgcn_mfma_f32_16x16x32_bf16(alf, whf, acc[et], 0, 0, 0);
            }
        }

        // -- epilogue: bias + stores (verified) --
        const size_t obase = ((size_t)(b * NB + n) * Tdim + (t0g + trow + lh * 4)) * EMB;
#pragma unroll
        for (int et = 0; et < 8; ++et) {
            const int   ec = et * 16 + lr;
            const float be = sb[ec];
#pragma unroll
            for (int r = 0; r < 4; ++r)
                out[obase + (size_t)r * EMB + ec] = acc[et][r] + be;
        }
        // next iter's stats barrier orders this GEMM's LDS reads before any
        // overwrite of this buffer (block-wide __syncthreads).
    }
}

// ---------------------------------------------------------------------------
// Fallback (exact round-1 kernel, known-passing): used only if the harness
// workspace is too small for the W pre-pass.
// ---------------------------------------------------------------------------
__global__ __launch_bounds__(NTHR, 3) void bandsplit_fallback(
    const float* __restrict__ xr, const float* __restrict__ xi,
    const float* __restrict__ lnw, const float* __restrict__ lnb,
    const float* __restrict__ fcw, const float* __restrict__ fcb,
    float* __restrict__ out)
{
    __shared__ __align__(16) float xs[FEAT][TILE_T];
    __shared__ __align__(16) unsigned short w_hi[EMB][FEAT];
    __shared__ __align__(16) unsigned short w_lo[EMB][FEAT];
    __shared__ float sb[EMB];
    __shared__ float slnw[FEAT];
    __shared__ float slnb[FEAT];
    __shared__ float smu[TILE_T];
    __shared__ float srs[TILE_T];

    const int tid  = threadIdx.x;
    const int lane = tid & 63;
    const int wav  = tid >> 6;
    const int bid  = blockIdx.x;
    const int tb   = bid & 15;
    const int n    = (bid >> 4) & 63;
    const int b    = bid >> 10;
    const int t0g  = tb * TILE_T;

#pragma unroll
    for (int k = 0; k < 4; ++k) {
        const int v  = tid + k * NTHR;
        const int f  = v >> 4;
        const int tq = v & 15;
        const int c  = f >> 5;
        const int w  = (f >> 1) & 15;
        const float* src = ((f & 1) ? xi : xr)
            + (((size_t)(b * Cdim + c) * Fdim + (n * BWb + w)) * Tdim + t0g + tq * 4);
        *(float4*)&xs[f][tq * 4] = *(const float4*)src;
    }

    if (tid < EMB)            sb[tid]              = fcb[n * EMB + tid];
    else if (tid < EMB + 64)  slnw[tid - EMB]      = lnw[n * FEAT + (tid - EMB)];
    else if (tid < EMB + 128) slnb[tid - EMB - 64] = lnb[n * FEAT + (tid - EMB - 64)];

    {
        const int e  = tid & 127;
        const int fh = (tid >> 7) * 32;
        const float* wsrc = fcw + (size_t)n * FEAT * EMB + e;
        float wv[32];
#pragma unroll
        for (int i = 0; i < 32; ++i)
            wv[i] = wsrc[(size_t)(fh + i) * EMB];
        char* const whb = (char*)&w_hi[0][0] + e * 128;
        char* const wlb = (char*)&w_lo[0][0] + e * 128;
#pragma unroll
        for (int cc = 0; cc < 4; ++cc) {
            unsigned hw[4], lw[4];
#pragma unroll
            for (int j = 0; j < 4; ++j) {
                const float x0 = wv[cc * 8 + 2 * j];
                const float x1 = wv[cc * 8 + 2 * j + 1];
                const unsigned short h0 = f2bf(x0), h1 = f2bf(x1);
                hw[j] = (unsigned)h0 | ((unsigned)h1 << 16);
                lw[j] = (unsigned)f2bf(x0 - bf2f(h0))
                      | ((unsigned)f2bf(x1 - bf2f(h1)) << 16);
            }
            const int cs = ((fh >> 3) + cc) ^ (e & 7);
            *(uint4*)(whb + cs * 16) = make_uint4(hw[0], hw[1], hw[2], hw[3]);
            *(uint4*)(wlb + cs * 16) = make_uint4(lw[0], lw[1], lw[2], lw[3]);
        }
    }
    __syncthreads();

    {
        const int t = tid >> 2;
        const int p = tid & 3;
        float s = 0.f, ss = 0.f;
#pragma unroll
        for (int j = 0; j < 16; ++j) {
            const float v = xs[p * 16 + j][t];
            s += v; ss += v * v;
        }
        s += __shfl_xor(s, 1); ss += __shfl_xor(ss, 1);
        s += __shfl_xor(s, 2); ss += __shfl_xor(ss, 2);
        if (p == 0) {
            const float mu  = s * (1.f / 64.f);
            const float var = ss * (1.f / 64.f) - mu * mu;
            smu[t] = mu;
            srs[t] = rsqrtf(var + EPSV);
        }
    }
    __syncthreads();

    uint4 hq[2], lq[2];
    {
        const int t = lane;
        const float mu = smu[t], rsv = srs[t];
#pragma unroll
        for (int u = 0; u < 2; ++u) {
            const int fc = wav + u * 4;
            float xvv[8];
#pragma unroll
            for (int j = 0; j < 8; ++j) xvv[j] = xs[fc * 8 + j][t];
            unsigned hw[4], lw[4];
#pragma unroll
            for (int j = 0; j < 4; ++j) {
                const int f0 = fc * 8 + 2 * j;
                const float xn0 = (xvv[2 * j]     - mu) * rsv * slnw[f0]     + slnb[f0];
                const float xn1 = (xvv[2 * j + 1] - mu) * rsv * slnw[f0 + 1] + slnb[f0 + 1];
                const unsigned short h0 = f2bf(xn0), h1 = f2bf(xn1);
                hw[j] = (unsigned)h0 | ((unsigned)h1 << 16);
                lw[j] = (unsigned)f2bf(xn0 - bf2f(h0))
                      | ((unsigned)f2bf(xn1 - bf2f(h1)) << 16);
            }
            hq[u] = make_uint4(hw[0], hw[1], hw[2], hw[3]);
            lq[u] = make_uint4(lw[0], lw[1], lw[2], lw[3]);
        }
    }
    __syncthreads();

    {
        char* const ab = (char*)&xs[0][0];
        const int t = lane;
#pragma unroll
        for (int u = 0; u < 2; ++u) {
            const int fc = wav + u * 4;
            const int cs = fc ^ (t & 7);
            *(uint4*)(ab +        t * 128 + cs * 16) = hq[u];
            *(uint4*)(ab + 8192 + t * 128 + cs * 16) = lq[u];
        }
    }
    __syncthreads();

    const int lr   = lane & 15;
    const int lh   = lane >> 4;
    const int trow = wav * 16;

    f32x4 acc[8];
    const f32x4 zero = {0.f, 0.f, 0.f, 0.f};
#pragma unroll
    for (int et = 0; et < 8; ++et) acc[et] = zero;

    const char* const ab  = (const char*)&xs[0][0];
    const char* const whb = (const char*)&w_hi[0][0];
    const char* const wlb = (const char*)&w_lo[0][0];

#pragma unroll
    for (int ks = 0; ks < 2; ++ks) {
        const int ta = trow + lr;
        const int ca = (ks * 4 + lh) ^ (ta & 7);
        const bf16x8 ahf = *(const bf16x8*)(ab +        ta * 128 + ca * 16);
        const bf16x8 alf = *(const bf16x8*)(ab + 8192 + ta * 128 + ca * 16);
#pragma unroll
        for (int et = 0; et < 8; ++et) {
            const int er = et * 16 + lr;
            const int cw = (ks * 4 + lh) ^ (er & 7);
            const bf16x8 whf = *(const bf16x8*)(whb + er * 128 + cw * 16);
            const bf16x8 wlf = *(const bf16x8*)(wlb + er * 128 + cw * 16);
            acc[et] = __builtin_amdgcn_mfma_f32_16x16x32_bf16(ahf, whf, acc[et], 0, 0, 0);
            acc[et] = __builtin_amdgcn_mfma_f32_16x16x32_bf16(ahf, wlf, acc[et], 0, 0, 0);
            acc[et] = __builtin_amdgcn_mfma_f32_16x16x32_bf16(alf, whf, acc[et], 0, 0, 0);
        }
    }

    const size_t obase = ((size_t)(b * NB + n) * Tdim + (t0g + trow + lh * 4)) * EMB;
#pragma unroll
    for (int et = 0; et < 8; ++et) {
        const int   ec = et * 16 + lr;
        const float be = sb[ec];
#pragma unroll
        for (int r = 0; r < 4; ++r)
            out[obase + (size_t)r * EMB + ec] = acc[et][r] + be;
    }
}

extern "C" void kernel_launch(void* const* d_in, const int* in_sizes, int n_in,
                              void* d_out, int out_size, void* d_ws, size_t ws_size,
                              hipStream_t stream) {
    const float* xr  = (const float*)d_in[0];
    const float* xi  = (const float*)d_in[1];
    const float* lnw = (const float*)d_in[2];
    const float* lnb = (const float*)d_in[3];
    const float* fcw = (const float*)d_in[4];
    const float* fcb = (const float*)d_in[5];
    float* out = (float*)d_out;

    const size_t wneed = (size_t)NB * 32768;        // 2 MB

    if (d_ws != nullptr && ws_size >= wneed) {
        unsigned char* ws = (unsigned char*)d_ws;
        const int grid = Bdim * NB * (Tdim / (TILE_T * NTILE));   // 2048
        hipLaunchKernelGGL(conv_w_kernel, dim3(NB), dim3(256), 0, stream, fcw, ws);
        hipLaunchKernelGGL(bandsplit_pipe, dim3(grid), dim3(NTHR), 0, stream,
                           xr, xi, lnw, lnb, ws, fcb, out);
    } else {
        const int grid = Bdim * NB * (Tdim / TILE_T);             // 8192
        hipLaunchKernelGGL(bandsplit_fallback, dim3(grid), dim3(NTHR), 0, stream,
                           xr, xi, lnw, lnb, fcw, fcb, out);
    }
}

// Round 5
// 374.447 us; speedup vs baseline: 1.0468x; 1.0468x over previous
//
#include <hip/hip_runtime.h>

// Problem constants (fixed by the reference)
#define Bdim   8
#define Cdim   2
#define Fdim   1024
#define Tdim   1024
#define NB     64
#define BWb    16
#define EMB    128
#define FEAT   64      // C * BW * 2
#define TILE_T 64
#define NTHR   256
#define EPSV   1e-5f

// MFMA fragment types (guide §3: 8 bf16 = 4 VGPRs, 4 f32 accum)
typedef __attribute__((ext_vector_type(8))) short bf16x8;
typedef __attribute__((ext_vector_type(4))) float f32x4;

// round-to-nearest-even fp32 -> bf16 (values are finite, no NaN handling needed)
__device__ __forceinline__ unsigned short f2bf(float x) {
    union { float f; unsigned u; } v; v.f = x;
    const unsigned r = v.u + 0x7FFFu + ((v.u >> 16) & 1u);
    return (unsigned short)(r >> 16);
}
__device__ __forceinline__ float bf2f(unsigned short b) {
    union { float f; unsigned u; } v; v.u = ((unsigned)b) << 16;
    return v.f;
}

// ---------------------------------------------------------------------------
// Pre-pass (verified round 3): fc_w fp32 [n][f][e] -> bf16 hi/lo in workspace,
// 32 KB per band, fragment XOR swizzle pre-applied so the main kernel does a
// LINEAR identity copy into LDS.
//   band n: bytes [n*32768, +16384) = hi, [+16384, +32768) = lo
//   within each: addr = e*128 + ((f/8) ^ (e&7))*16
// ---------------------------------------------------------------------------
__global__ __launch_bounds__(256) void conv_w_kernel(
    const float* __restrict__ fcw, unsigned char* __restrict__ ws)
{
    const int n  = blockIdx.x;
    const int e  = threadIdx.x & 127;
    const int fh = (threadIdx.x >> 7) * 32;
    const float* wsrc = fcw + (size_t)n * FEAT * EMB + e;
    float wv[32];
#pragma unroll
    for (int i = 0; i < 32; ++i)
        wv[i] = wsrc[(size_t)(fh + i) * EMB];

    char* const whb = (char*)ws + (size_t)n * 32768 + e * 128;
    char* const wlb = whb + 16384;
#pragma unroll
    for (int cc = 0; cc < 4; ++cc) {
        unsigned hw[4], lw[4];
#pragma unroll
        for (int j = 0; j < 4; ++j) {
            const float x0 = wv[cc * 8 + 2 * j];
            const float x1 = wv[cc * 8 + 2 * j + 1];
            const unsigned short h0 = f2bf(x0), h1 = f2bf(x1);
            hw[j] = (unsigned)h0 | ((unsigned)h1 << 16);
            lw[j] = (unsigned)f2bf(x0 - bf2f(h0))
                  | ((unsigned)f2bf(x1 - bf2f(h1)) << 16);
        }
        const int cs = ((fh >> 3) + cc) ^ (e & 7);
        *(uint4*)(whb + cs * 16) = make_uint4(hw[0], hw[1], hw[2], hw[3]);
        *(uint4*)(wlb + cs * 16) = make_uint4(lw[0], lw[1], lw[2], lw[3]);
    }
}

// ---------------------------------------------------------------------------
// Main kernel (round-3 verified base; single changed lane = GEMM wave
// decomposition). Grid 8192 x 256 thr, one 64-t tile per block, 3 blocks/CU.
// GEMM re-partition: wave owns ALL 64 t x a PRIVATE 32-e strip
//   (e in [wav*32, wav*32+32)). Its 8 W fragments (2 e-subtiles x 2 k-halves
//   x hi/lo) are loaded to REGISTERS right after the first barrier — their
//   LDS reads overlap stats/norm — so the GEMM window issues only 16 A-reads
//   (vs 36 reads before, with 4x cross-wave W redundancy eliminated).
// LDS: xs 16K + W 32K + ~1.3K = 49.3 KB -> 3 blocks/CU.
// ---------------------------------------------------------------------------
__global__ __launch_bounds__(NTHR, 3) void bandsplit_mfma(
    const float* __restrict__ xr, const float* __restrict__ xi,
    const float* __restrict__ lnw, const float* __restrict__ lnb,
    const unsigned char* __restrict__ whl, const float* __restrict__ fcb,
    float* __restrict__ out)
{
    __shared__ __align__(16) float xs[FEAT][TILE_T];            // 16 KB
    __shared__ __align__(16) unsigned short w_hl[2][EMB][FEAT]; // 32 KB (pre-swizzled)
    __shared__ float sb[EMB];
    __shared__ float slnw[FEAT];
    __shared__ float slnb[FEAT];
    __shared__ float smu[TILE_T];
    __shared__ float srs[TILE_T];

    const int tid  = threadIdx.x;
    const int lane = tid & 63;
    const int wav  = tid >> 6;
    const int bid  = blockIdx.x;
    const int tb   = bid & 15;          // t-tile
    const int n    = (bid >> 4) & 63;   // band
    const int b    = bid >> 10;         // batch
    const int t0g  = tb * TILE_T;

    // ---- Phase 1: stage x tile (fp32 [f][t], coalesced along t) ----
#pragma unroll
    for (int k = 0; k < 4; ++k) {
        const int v  = tid + k * NTHR;      // 0..1023
        const int f  = v >> 4;              // 0..63
        const int tq = v & 15;
        const int c  = f >> 5;
        const int w  = (f >> 1) & 15;
        const float* src = ((f & 1) ? xi : xr)
            + (((size_t)(b * Cdim + c) * Fdim + (n * BWb + w)) * Tdim + t0g + tq * 4);
        *(float4*)&xs[f][tq * 4] = *(const float4*)src;
    }

    if (tid < EMB)            sb[tid]              = fcb[n * EMB + tid];
    else if (tid < EMB + 64)  slnw[tid - EMB]      = lnw[n * FEAT + (tid - EMB)];
    else if (tid < EMB + 128) slnb[tid - EMB - 64] = lnb[n * FEAT + (tid - EMB - 64)];

    // ---- Phase 1b: linear identity copy of the pre-converted band image ----
    {
        const uint4* wsrc = (const uint4*)(whl + (size_t)n * 32768);
        uint4* wdst = (uint4*)&w_hl[0][0][0];
#pragma unroll
        for (int k = 0; k < 8; ++k)
            wdst[tid + k * NTHR] = wsrc[tid + k * NTHR];
    }
    __syncthreads();

    // ---- W fragments -> registers (once per block; overlaps stats/norm).
    // Wave's private e-strip: e = wav*32 + et2*16 + lr, k-half lh.
    const int lr = lane & 15;
    const int lh = lane >> 4;
    const char* const whb = (const char*)&w_hl[0][0][0];
    const char* const wlb = whb + 16384;

    bf16x8 wf_h[2][2], wf_l[2][2];      // [et2][ks] — 32 VGPRs
#pragma unroll
    for (int et2 = 0; et2 < 2; ++et2) {
        const int er = wav * 32 + et2 * 16 + lr;
#pragma unroll
        for (int ks = 0; ks < 2; ++ks) {
            const int cw = (ks * 4 + lh) ^ (er & 7);
            wf_h[et2][ks] = *(const bf16x8*)(whb + er * 128 + cw * 16);
            wf_l[et2][ks] = *(const bf16x8*)(wlb + er * 128 + cw * 16);
        }
    }

    // ---- Phase 2: per-row LN stats (verified) ----
    {
        const int t = tid >> 2;
        const int p = tid & 3;
        float s = 0.f, ss = 0.f;
#pragma unroll
        for (int j = 0; j < 16; ++j) {
            const float v = xs[p * 16 + j][t];
            s += v; ss += v * v;
        }
        s += __shfl_xor(s, 1); ss += __shfl_xor(ss, 1);
        s += __shfl_xor(s, 2); ss += __shfl_xor(ss, 2);
        if (p == 0) {
            const float mu  = s * (1.f / 64.f);
            const float var = ss * (1.f / 64.f) - mu * mu;
            smu[t] = mu;
            srs[t] = rsqrtf(var + EPSV);
        }
    }
    __syncthreads();

    // ---- Phase 3: normalize + transpose + bf16 hi/lo split (verified) ----
    uint4 hq[2], lq[2];
    {
        const int t = lane;
        const float mu = smu[t], rsv = srs[t];
#pragma unroll
        for (int u = 0; u < 2; ++u) {
            const int fc = wav + u * 4;     // f-chunk 0..7
            float xv[8];
#pragma unroll
            for (int j = 0; j < 8; ++j) xv[j] = xs[fc * 8 + j][t];
            unsigned hw[4], lw[4];
#pragma unroll
            for (int j = 0; j < 4; ++j) {
                const int f0 = fc * 8 + 2 * j;
                const float xn0 = (xv[2 * j]     - mu) * rsv * slnw[f0]     + slnb[f0];
                const float xn1 = (xv[2 * j + 1] - mu) * rsv * slnw[f0 + 1] + slnb[f0 + 1];
                const unsigned short h0 = f2bf(xn0), h1 = f2bf(xn1);
                hw[j] = (unsigned)h0 | ((unsigned)h1 << 16);
                lw[j] = (unsigned)f2bf(xn0 - bf2f(h0))
                      | ((unsigned)f2bf(xn1 - bf2f(h1)) << 16);
            }
            hq[u] = make_uint4(hw[0], hw[1], hw[2], hw[3]);
            lq[u] = make_uint4(lw[0], lw[1], lw[2], lw[3]);
        }
    }
    __syncthreads();   // every thread finished reading xs -> safe to overlay

    {
        char* const ab = (char*)&xs[0][0];
        const int t = lane;
#pragma unroll
        for (int u = 0; u < 2; ++u) {
            const int fc = wav + u * 4;
            const int cs = fc ^ (t & 7);
            *(uint4*)(ab +        t * 128 + cs * 16) = hq[u];   // a_hi[t][fc*8..]
            *(uint4*)(ab + 8192 + t * 128 + cs * 16) = lq[u];   // a_lo[t][fc*8..]
        }
    }
    __syncthreads();

    // ---- Phase 4: MFMA GEMM, wave = 64t x 32e strip, W in regs.
    // A: row = lane&15 (t), k = lh*8+j ; D: col = lane&15 (e),
    // row = lh*4+reg (t). 16 A ds_read_b128 total; 48 MFMA (unchanged).
    const char* const ab = (const char*)&xs[0][0];

    f32x4 acc[4][2];                    // [tg][et2]
    const f32x4 zero = {0.f, 0.f, 0.f, 0.f};
#pragma unroll
    for (int tg = 0; tg < 4; ++tg)
#pragma unroll
        for (int et2 = 0; et2 < 2; ++et2) acc[tg][et2] = zero;

#pragma unroll
    for (int tg = 0; tg < 4; ++tg) {
        const int ta = tg * 16 + lr;
#pragma unroll
        for (int ks = 0; ks < 2; ++ks) {
            const int ca = (ks * 4 + lh) ^ (ta & 7);
            const bf16x8 ahf = *(const bf16x8*)(ab +        ta * 128 + ca * 16);
            const bf16x8 alf = *(const bf16x8*)(ab + 8192 + ta * 128 + ca * 16);
#pragma unroll
            for (int et2 = 0; et2 < 2; ++et2) {
                acc[tg][et2] = __builtin_amdgcn_mfma_f32_16x16x32_bf16(ahf, wf_h[et2][ks], acc[tg][et2], 0, 0, 0);
                acc[tg][et2] = __builtin_amdgcn_mfma_f32_16x16x32_bf16(ahf, wf_l[et2][ks], acc[tg][et2], 0, 0, 0);
                acc[tg][et2] = __builtin_amdgcn_mfma_f32_16x16x32_bf16(alf, wf_h[et2][ks], acc[tg][et2], 0, 0, 0);
            }
        }
    }

    // ---- Epilogue: bias + stores (64B contiguous segments per instr) ----
    const size_t orow0 = (size_t)(b * NB + n) * Tdim + t0g;
#pragma unroll
    for (int tg = 0; tg < 4; ++tg) {
        const size_t obase = (orow0 + tg * 16 + lh * 4) * EMB;
#pragma unroll
        for (int et2 = 0; et2 < 2; ++et2) {
            const int   ec = wav * 32 + et2 * 16 + lr;
            const float be = sb[ec];
#pragma unroll
            for (int r = 0; r < 4; ++r)
                out[obase + (size_t)r * EMB + ec] = acc[tg][et2][r] + be;
        }
    }
}

// ---------------------------------------------------------------------------
// Fallback (exact round-1 kernel, known-passing): used only if the harness
// workspace is too small for the W pre-pass.
// ---------------------------------------------------------------------------
__global__ __launch_bounds__(NTHR, 3) void bandsplit_fallback(
    const float* __restrict__ xr, const float* __restrict__ xi,
    const float* __restrict__ lnw, const float* __restrict__ lnb,
    const float* __restrict__ fcw, const float* __restrict__ fcb,
    float* __restrict__ out)
{
    __shared__ __align__(16) float xs[FEAT][TILE_T];
    __shared__ __align__(16) unsigned short w_hi[EMB][FEAT];
    __shared__ __align__(16) unsigned short w_lo[EMB][FEAT];
    __shared__ float sb[EMB];
    __shared__ float slnw[FEAT];
    __shared__ float slnb[FEAT];
    __shared__ float smu[TILE_T];
    __shared__ float srs[TILE_T];

    const int tid  = threadIdx.x;
    const int lane = tid & 63;
    const int wav  = tid >> 6;
    const int bid  = blockIdx.x;
    const int tb   = bid & 15;
    const int n    = (bid >> 4) & 63;
    const int b    = bid >> 10;
    const int t0g  = tb * TILE_T;

#pragma unroll
    for (int k = 0; k < 4; ++k) {
        const int v  = tid + k * NTHR;
        const int f  = v >> 4;
        const int tq = v & 15;
        const int c  = f >> 5;
        const int w  = (f >> 1) & 15;
        const float* src = ((f & 1) ? xi : xr)
            + (((size_t)(b * Cdim + c) * Fdim + (n * BWb + w)) * Tdim + t0g + tq * 4);
        *(float4*)&xs[f][tq * 4] = *(const float4*)src;
    }

    if (tid < EMB)            sb[tid]              = fcb[n * EMB + tid];
    else if (tid < EMB + 64)  slnw[tid - EMB]      = lnw[n * FEAT + (tid - EMB)];
    else if (tid < EMB + 128) slnb[tid - EMB - 64] = lnb[n * FEAT + (tid - EMB - 64)];

    {
        const int e  = tid & 127;
        const int fh = (tid >> 7) * 32;
        const float* wsrc = fcw + (size_t)n * FEAT * EMB + e;
        float wv[32];
#pragma unroll
        for (int i = 0; i < 32; ++i)
            wv[i] = wsrc[(size_t)(fh + i) * EMB];
        char* const whb = (char*)&w_hi[0][0] + e * 128;
        char* const wlb = (char*)&w_lo[0][0] + e * 128;
#pragma unroll
        for (int cc = 0; cc < 4; ++cc) {
            unsigned hw[4], lw[4];
#pragma unroll
            for (int j = 0; j < 4; ++j) {
                const float x0 = wv[cc * 8 + 2 * j];
                const float x1 = wv[cc * 8 + 2 * j + 1];
                const unsigned short h0 = f2bf(x0), h1 = f2bf(x1);
                hw[j] = (unsigned)h0 | ((unsigned)h1 << 16);
                lw[j] = (unsigned)f2bf(x0 - bf2f(h0))
                      | ((unsigned)f2bf(x1 - bf2f(h1)) << 16);
            }
            const int cs = ((fh >> 3) + cc) ^ (e & 7);
            *(uint4*)(whb + cs * 16) = make_uint4(hw[0], hw[1], hw[2], hw[3]);
            *(uint4*)(wlb + cs * 16) = make_uint4(lw[0], lw[1], lw[2], lw[3]);
        }
    }
    __syncthreads();

    {
        const int t = tid >> 2;
        const int p = tid & 3;
        float s = 0.f, ss = 0.f;
#pragma unroll
        for (int j = 0; j < 16; ++j) {
            const float v = xs[p * 16 + j][t];
            s += v; ss += v * v;
        }
        s += __shfl_xor(s, 1); ss += __shfl_xor(ss, 1);
        s += __shfl_xor(s, 2); ss += __shfl_xor(ss, 2);
        if (p == 0) {
            const float mu  = s * (1.f / 64.f);
            const float var = ss * (1.f / 64.f) - mu * mu;
            smu[t] = mu;
            srs[t] = rsqrtf(var + EPSV);
        }
    }
    __syncthreads();

    uint4 hq[2], lq[2];
    {
        const int t = lane;
        const float mu = smu[t], rsv = srs[t];
#pragma unroll
        for (int u = 0; u < 2; ++u) {
            const int fc = wav + u * 4;
            float xvv[8];
#pragma unroll
            for (int j = 0; j < 8; ++j) xvv[j] = xs[fc * 8 + j][t];
            unsigned hw[4], lw[4];
#pragma unroll
            for (int j = 0; j < 4; ++j) {
                const int f0 = fc * 8 + 2 * j;
                const float xn0 = (xvv[2 * j]     - mu) * rsv * slnw[f0]     + slnb[f0];
                const float xn1 = (xvv[2 * j + 1] - mu) * rsv * slnw[f0 + 1] + slnb[f0 + 1];
                const unsigned short h0 = f2bf(xn0), h1 = f2bf(xn1);
                hw[j] = (unsigned)h0 | ((unsigned)h1 << 16);
                lw[j] = (unsigned)f2bf(xn0 - bf2f(h0))
                      | ((unsigned)f2bf(xn1 - bf2f(h1)) << 16);
            }
            hq[u] = make_uint4(hw[0], hw[1], hw[2], hw[3]);
            lq[u] = make_uint4(lw[0], lw[1], lw[2], lw[3]);
        }
    }
    __syncthreads();

    {
        char* const ab = (char*)&xs[0][0];
        const int t = lane;
#pragma unroll
        for (int u = 0; u < 2; ++u) {
            const int fc = wav + u * 4;
            const int cs = fc ^ (t & 7);
            *(uint4*)(ab +        t * 128 + cs * 16) = hq[u];
            *(uint4*)(ab + 8192 + t * 128 + cs * 16) = lq[u];
        }
    }
    __syncthreads();

    const int lr   = lane & 15;
    const int lh   = lane >> 4;
    const int trow = wav * 16;

    f32x4 acc[8];
    const f32x4 zero = {0.f, 0.f, 0.f, 0.f};
#pragma unroll
    for (int et = 0; et < 8; ++et) acc[et] = zero;

    const char* const ab  = (const char*)&xs[0][0];
    const char* const whb = (const char*)&w_hi[0][0];
    const char* const wlb = (const char*)&w_lo[0][0];

#pragma unroll
    for (int ks = 0; ks < 2; ++ks) {
        const int ta = trow + lr;
        const int ca = (ks * 4 + lh) ^ (ta & 7);
        const bf16x8 ahf = *(const bf16x8*)(ab +        ta * 128 + ca * 16);
        const bf16x8 alf = *(const bf16x8*)(ab + 8192 + ta * 128 + ca * 16);
#pragma unroll
        for (int et = 0; et < 8; ++et) {
            const int er = et * 16 + lr;
            const int cw = (ks * 4 + lh) ^ (er & 7);
            const bf16x8 whf = *(const bf16x8*)(whb + er * 128 + cw * 16);
            const bf16x8 wlf = *(const bf16x8*)(wlb + er * 128 + cw * 16);
            acc[et] = __builtin_amdgcn_mfma_f32_16x16x32_bf16(ahf, whf, acc[et], 0, 0, 0);
            acc[et] = __builtin_amdgcn_mfma_f32_16x16x32_bf16(ahf, wlf, acc[et], 0, 0, 0);
            acc[et] = __builtin_amdgcn_mfma_f32_16x16x32_bf16(alf, whf, acc[et], 0, 0, 0);
        }
    }

    const size_t obase = ((size_t)(b * NB + n) * Tdim + (t0g + trow + lh * 4)) * EMB;
#pragma unroll
    for (int et = 0; et < 8; ++et) {
        const int   ec = et * 16 + lr;
        const float be = sb[ec];
#pragma unroll
        for (int r = 0; r < 4; ++r)
            out[obase + (size_t)r * EMB + ec] = acc[et][r] + be;
    }
}

extern "C" void kernel_launch(void* const* d_in, const int* in_sizes, int n_in,
                              void* d_out, int out_size, void* d_ws, size_t ws_size,
                              hipStream_t stream) {
    const float* xr  = (const float*)d_in[0];
    const float* xi  = (const float*)d_in[1];
    const float* lnw = (const float*)d_in[2];
    const float* lnb = (const float*)d_in[3];
    const float* fcw = (const float*)d_in[4];
    const float* fcb = (const float*)d_in[5];
    float* out = (float*)d_out;

    const int grid = Bdim * NB * (Tdim / TILE_T);   // 8192
    const size_t wneed = (size_t)NB * 32768;        // 2 MB

    if (d_ws != nullptr && ws_size >= wneed) {
        unsigned char* ws = (unsigned char*)d_ws;
        hipLaunchKernelGGL(conv_w_kernel, dim3(NB), dim3(256), 0, stream, fcw, ws);
        hipLaunchKernelGGL(bandsplit_mfma, dim3(grid), dim3(NTHR), 0, stream,
                           xr, xi, lnw, lnb, ws, fcb, out);
    } else {
        hipLaunchKernelGGL(bandsplit_fallback, dim3(grid), dim3(NTHR), 0, stream,
                           xr, xi, lnw, lnb, fcw, fcb, out);
    }
}